// Round 8
// baseline (18029.791 us; speedup 1.0000x reference)
//
#include <hip/hip_runtime.h>
#include <stdint.h>
#include <math.h>

// Problem constants (match reference)
#define BB 128
#define NN 2048
#define DD 2
#define ROWLEN (2 + NN * DD + 5)   // 4103
#define SIGMA_C 0.001f
#define HALF_CNT 262144u           // B*N*D / 2

// ---------------------------------------------------------------------------
// R7 post-mortem: LDS-stash approaches are structurally losing. R7 passed at
// 12ms but still re-fetched ~1GB/dispatch of spilled loop-invariants
// (FETCH 970MB vs WRITE 81MB = spill-once, reload-every-step), occupancy 21%.
// Root cause across R0-R7: h3 (32 regs) living across the fwd->bwd gap pushes
// peak liveness past every workable VGPR budget.
// This version ELIMINATES the gap algebraically (no LDS at all):
//   - g4_j = g5 * (W5_j * d4_j) is rank-1 in the SCALAR g5. During S_H4,
//     h4 is a per-j TEMP: fold z5 += W5_j*h4_j and v_j = W5_j*d4_j
//     immediately -> h4 never becomes live state.
//   - After g5: g3_k = (g5 * sum_j W4[j][k]*v_j) * d3_k, consuming h3_k as
//     each g3_k is produced -> h3-remaining + g3-produced stays exactly 32.
// Peak liveness ~72 regs (S_H3: h2+h3=64; g3-loop: 32+v:16; S_G2: g3+a+h1=64).
// No LDS -> no ordering hazards, no fences, no occupancy charge.
// NOT bit-identical: g5 factored out of the g3 reduction (~1 ulp f32 per g3
// element); output is scored in bf16 (quantum 0.03125, threshold 0.12125).
// All other op sequences identical to the passing kernels.
// bidx = blockIdx.x>>3 is manifestly wave-uniform -> row scalars in SGPRs.
// __launch_bounds__(256,4): VGPR cap 128 (grid supplies exactly 4 waves/EU,
// so the cap is free); 72 structural << 128 -> no spill.
// ---------------------------------------------------------------------------

// repetition macros: A-suffix for outer loops, B-suffix for inner loops
// (cpp will not re-expand a macro inside itself, so the copies are required)
#define R16A(M) M(0) M(1) M(2) M(3) M(4) M(5) M(6) M(7) M(8) M(9) M(10) M(11) M(12) M(13) M(14) M(15)
#define R32A(M) R16A(M) M(16) M(17) M(18) M(19) M(20) M(21) M(22) M(23) M(24) M(25) M(26) M(27) M(28) M(29) M(30) M(31)
#define R16B(M) M(0) M(1) M(2) M(3) M(4) M(5) M(6) M(7) M(8) M(9) M(10) M(11) M(12) M(13) M(14) M(15)
#define R32B(M) R16B(M) M(16) M(17) M(18) M(19) M(20) M(21) M(22) M(23) M(24) M(25) M(26) M(27) M(28) M(29) M(30) M(31)

#define ELU(z) ((z) > 0.0f ? (z) : (__expf(z) - 1.0f))
// elu derivative from elu output: d = (z>0) ? 1 : exp(z); for z<=0,
// h = exp(z)-1  =>  d = h+1 (bit-matches prior kernels' DFROMH)
#define DFROMH(h) ((h) > 0.0f ? 1.0f : (h) + 1.0f)

__device__ __forceinline__ uint32_t rotl32(uint32_t v, uint32_t r) {
  return (v << r) | (v >> (32u - r));
}

// JAX threefry2x32 (20 rounds), matches jax/_src/prng.py
__device__ __forceinline__ void tf2x32(uint32_t k0, uint32_t k1,
                                       uint32_t x0, uint32_t x1,
                                       uint32_t& o0, uint32_t& o1) {
  uint32_t k2 = k0 ^ k1 ^ 0x1BD11BDAu;
  x0 += k0; x1 += k1;
#define TF_R(r) { x0 += x1; x1 = rotl32(x1, r); x1 ^= x0; }
  TF_R(13) TF_R(15) TF_R(26) TF_R(6)   x0 += k1; x1 += k2 + 1u;
  TF_R(17) TF_R(29) TF_R(16) TF_R(24)  x0 += k2; x1 += k0 + 2u;
  TF_R(13) TF_R(15) TF_R(26) TF_R(6)   x0 += k0; x1 += k1 + 3u;
  TF_R(17) TF_R(29) TF_R(16) TF_R(24)  x0 += k1; x1 += k2 + 4u;
  TF_R(13) TF_R(15) TF_R(26) TF_R(6)   x0 += k2; x1 += k0 + 5u;
#undef TF_R
  o0 = x0; o1 = x1;
}

// XLA f32 ErfInv (Giles 2012 polynomial) — what lax.erf_inv lowers to
__device__ __forceinline__ float erfinv_f32(float x) {
  float w = -log1pf(-(x * x));
  float p;
  if (w < 5.0f) {
    w = w - 2.5f;
    p = 2.81022636e-08f;
    p = fmaf(p, w, 3.43273939e-07f);
    p = fmaf(p, w, -3.5233877e-06f);
    p = fmaf(p, w, -4.39150654e-06f);
    p = fmaf(p, w, 0.00021858087f);
    p = fmaf(p, w, -0.00125372503f);
    p = fmaf(p, w, -0.00417768164f);
    p = fmaf(p, w, 0.246640727f);
    p = fmaf(p, w, 1.50140941f);
  } else {
    w = sqrtf(w) - 3.0f;
    p = -0.000200214257f;
    p = fmaf(p, w, 0.000100950558f);
    p = fmaf(p, w, 0.00134934322f);
    p = fmaf(p, w, -0.00367342844f);
    p = fmaf(p, w, 0.00573950773f);
    p = fmaf(p, w, -0.0076224613f);
    p = fmaf(p, w, 0.00943887047f);
    p = fmaf(p, w, 1.00167406f);
    p = fmaf(p, w, 2.83297682f);
  }
  return p * x;
}

// jax.random.normal for one flat element index f under key (k0,k1)
__device__ __forceinline__ float jax_normal_elem(uint32_t k0, uint32_t k1,
                                                 uint32_t f) {
  uint32_t o0, o1, bits;
  if (f < HALF_CNT) {
    tf2x32(k0, k1, f, f + HALF_CNT, o0, o1);
    bits = o0;
  } else {
    tf2x32(k0, k1, f - HALF_CNT, f, o0, o1);
    bits = o1;
  }
  float u01 = __uint_as_float((bits >> 9) | 0x3f800000u) - 1.0f;
  const float lo = -0.99999994f;           // nextafter(-1, 0) in f32
  float v = fmaxf(lo, fmaf(u01, 2.0f, lo));
  return 1.41421356237309515f * erfinv_f32(v);
}

__global__ __launch_bounds__(256, 4)
void phinn_kernel(
    const float* __restrict__ x,
    const float* __restrict__ W1, const float* __restrict__ b1,
    const float* __restrict__ W2, const float* __restrict__ b2,
    const float* __restrict__ W3, const float* __restrict__ b3,
    const float* __restrict__ W4, const float* __restrict__ b4,
    const float* __restrict__ W5, const float* __restrict__ b5,
    const float* __restrict__ Wt,
    const float* __restrict__ dtp, const int* __restrict__ nstepsp,
    float* __restrict__ out) {
  const int tx = threadIdx.x;
  const int bx = blockIdx.x;
  const int tid = (bx << 8) + tx;            // 0 .. B*N-1
  const int bidx = bx >> 3;                  // uniform per block (N/256 = 8)
  const int nidx = ((bx & 7) << 8) + tx;

  const float dt = dtp[0];
  const int nsteps = nstepsp[0];
  const float sqdt = sqrtf(dt);

  const float* xr = x + (size_t)bidx * ROWLEN;   // uniform -> s_loads
  float tt = xr[0];
  float y0 = xr[2 + nidx * 2 + 0];
  float y1 = xr[2 + nidx * 2 + 1];
  const float tcrit = xr[2 + NN * DD + 0];

  // Hoisted tilt products: same fmafs as the in-loop original, with the
  // pre/post select moved AFTER the arithmetic (bit-identical values).
  const float sp0 = xr[2 + NN * DD + 1];
  const float sp1 = xr[2 + NN * DD + 2];
  const float sq0 = xr[2 + NN * DD + 3];
  const float sq1 = xr[2 + NN * DD + 4];
  const float wt00 = Wt[0], wt01 = Wt[1], wt10 = Wt[2], wt11 = Wt[3];
  const float tp0 = fmaf(sp0, wt00, sp1 * wt01);
  const float tp1 = fmaf(sp0, wt10, sp1 * wt11);
  const float tq0 = fmaf(sq0, wt00, sq1 * wt01);
  const float tq1 = fmaf(sq0, wt10, sq1 * wt11);

  const uint32_t f0 = (uint32_t)(tid << 1);  // flat idx of component 0

  // named scalar activation state (no arrays, no vectors, no LDS)
#define D_H1(j) float h1_##j;
#define D_H2(j) float h2_##j;
#define D_H3(j) float h3_##j;
#define D_V(j)  float v_##j;
#define D_G3(j) float g3_##j;
#define D_A(j)  float a_##j;
  R16A(D_H1)
  R32A(D_H2)
  R32A(D_H3)
  R16A(D_V)
  R32A(D_G3)
  R16A(D_A)

  for (int i = 0; i < nsteps; ++i) {
    // ---- forward: 2 -> 16 -> 32 -> 32 -> 16 -> 1 ----
    // h1 (dropped after h2; recomputed bit-identically in backward)
#define S_H1(j) { float z = fmaf(W1[2*j+0], y0, fmaf(W1[2*j+1], y1, b1[j])); h1_##j = ELU(z); }
    R16A(S_H1)

    // h2 (dropped after h3; recomputed per-element in backward)
#define MAC_H2(k) z = fmaf(W2[16*J+k], h1_##k, z);
#define S_H2(j) { const int J = j; float z = b2[J]; R16B(MAC_H2) h2_##j = ELU(z); }
    R32A(S_H2)

    // h3 (kept in regs; consumed elementwise by the g3 loop below)
#define MAC_H3(k) z = fmaf(W3[32*J+k], h2_##k, z);
#define S_H3(j) { const int J = j; float z = b3[J]; R32B(MAC_H3) h3_##j = ELU(z); }
    R32A(S_H3)

    // layer 4 + 5 fused: h4 is a per-j TEMP. z5 accumulates in the same
    // j-order as the original separate loop (bit-identical z5); v_j = W5_j*d4_j
    // replaces h4/g4 as live state (16 regs instead of 16+16).
    float z5 = b5[0];
#define MAC_H4(k) z = fmaf(W4[32*J+k], h3_##k, z);
#define S_H4V(j) { const int J = j; float z = b4[J]; R32B(MAC_H4) \
      float h4t = ELU(z); \
      z5 = fmaf(W5[J], h4t, z5); \
      v_##j = W5[J] * DFROMH(h4t); }
    R16A(S_H4V)

    // d softplus = sigmoid
    float g5 = 1.0f / (1.0f + __expf(-z5));

    // ---- backward (input-gradient) ----
    // g3_k = (g5 * sum_j W4[j][k]*v_j) * d3_k; h3_k dies as g3_k is born
    // (live h3-remaining + g3-produced stays exactly 32).
#define MAC_U(j) r = fmaf(W4[32*j+K], v_##j, r);
#define S_G3(k) { const int K = k; float r = 0.0f; R16B(MAC_U) \
      g3_##k = (g5 * r) * DFROMH(h3_##k); }
    R32A(S_G3)

    // recompute h1 from y (identical op sequence -> bit-identical values)
#define S_RH1(j) { float z = fmaf(W1[2*j+0], y0, fmaf(W1[2*j+1], y1, b1[j])); h1_##j = ELU(z); }
    R16A(S_RH1)

    // fused g2 -> a: for each j, produce g2_j (recomputing h2_j bit-exactly),
    // then immediately fold it into a_k = sum_j W2[16j+k]*g2_j.
#define Z_A(k) a_##k = 0.0f;
    R16A(Z_A)
#define MAC_T(i) tsum = fmaf(W3[32*i+J], g3_##i, tsum);
#define MAC_Z2(k) z2 = fmaf(W2[16*J+k], h1_##k, z2);
#define MAC_A(k) a_##k = fmaf(W2[16*J+k], g2j, a_##k);
#define S_G2(j) { const int J = j; \
      float tsum = 0.0f; R32B(MAC_T) \
      float z2 = b2[J]; R16B(MAC_Z2) \
      float h2r = ELU(z2); \
      float g2j = tsum * DFROMH(h2r); \
      R16B(MAC_A) }
    R32A(S_G2)

    // g1 and input-gradient, fused (same fmaf chain order as original)
    float gy0 = 0.0f, gy1 = 0.0f;
#define MAC_GY(j) { float g1j = a_##j * DFROMH(h1_##j); \
      gy0 = fmaf(W1[2*j+0], g1j, gy0); \
      gy1 = fmaf(W1[2*j+1], g1j, gy1); }
    R16A(MAC_GY)

    // ---- tilt (hoisted products, select only) ----
    bool pre = tt < tcrit;
    float tilt0 = pre ? tp0 : tq0;
    float tilt1 = pre ? tp1 : tq1;

    // ---- per-step key, computed only now so k0/k1 aren't live in the MLP
    // fold_in(key(42), i) = threefry((0,42), (0,i)); uniform across threads
    uint32_t k0, k1;
    tf2x32(0u, 42u, 0u, (uint32_t)i, k0, k1);

    // ---- noise (exact JAX threefry normal) ----
    float nz0 = jax_normal_elem(k0, k1, f0);
    float nz1 = jax_normal_elem(k0, k1, f0 + 1u);

    // ---- Euler-Maruyama update ----
    float drift0 = -(gy0 + tilt0);
    float drift1 = -(gy1 + tilt1);
    y0 = y0 + drift0 * dt + SIGMA_C * (nz0 * sqdt);
    y1 = y1 + drift1 * dt + SIGMA_C * (nz1 * sqdt);
    tt += dt;
  }

  out[(size_t)tid * 2 + 0] = y0;
  out[(size_t)tid * 2 + 1] = y1;
}

extern "C" void kernel_launch(void* const* d_in, const int* in_sizes, int n_in,
                              void* d_out, int out_size, void* d_ws,
                              size_t ws_size, hipStream_t stream) {
  const float* x  = (const float*)d_in[0];
  const float* W1 = (const float*)d_in[1];
  const float* b1 = (const float*)d_in[2];
  const float* W2 = (const float*)d_in[3];
  const float* b2 = (const float*)d_in[4];
  const float* W3 = (const float*)d_in[5];
  const float* b3 = (const float*)d_in[6];
  const float* W4 = (const float*)d_in[7];
  const float* b4 = (const float*)d_in[8];
  const float* W5 = (const float*)d_in[9];
  const float* b5 = (const float*)d_in[10];
  const float* Wt = (const float*)d_in[11];
  const float* dt = (const float*)d_in[12];
  const int* nsteps = (const int*)d_in[13];
  float* out = (float*)d_out;

  dim3 grid((BB * NN) / 256);
  dim3 block(256);
  hipLaunchKernelGGL(phinn_kernel, grid, block, 0, stream,
                     x, W1, b1, W2, b2, W3, b3, W4, b4, W5, b5, Wt, dt, nsteps,
                     out);
}

// Round 9
// 16444.211 us; speedup vs baseline: 1.0964x; 1.0964x over previous
//
#include <hip/hip_runtime.h>
#include <stdint.h>
#include <math.h>

// Problem constants (match reference)
#define BB 128
#define NN 2048
#define DD 2
#define ROWLEN (2 + NN * DD + 5)   // 4103
#define SIGMA_C 0.001f
#define HALF_CNT 262144u           // B*N*D / 2

// ---------------------------------------------------------------------------
// R8 post-mortem: the lean algebraic structure (no LDS, h4/g4 folded into
// v_j, g3 consuming h3 in place; structural liveness ~75-85) is right, but
// __launch_bounds__(256,4) made the allocator jump to the 8-waves/EU step:
// VGPR=64 -> ~20 regs respilled every step -> 11.8GB HBM traffic, 18ms.
// Identical behavior to R1's waves_per_eu(4,4) (also 64/12.3GB).
// Empirical allocator table (9 rounds): only __launch_bounds__(256,2) lands
// VGPR in the 65-128 band (R2:88, R3:116, R7:100) = the 4-waves/EU hardware
// occupancy step. Those rounds spilled only because their structures needed
// more than the pick; this structure needs ~85.
// This round changes ONE variable: launch bound -> (256,2). Structure is
// byte-identical to the passing R8 kernel.
//   - g4_j = g5 * (W5_j * d4_j) rank-1 factorization: h4 is a per-j temp,
//     z5/v_j fold immediately -> h4 never live.
//   - g3_k = (g5 * sum_j W4[j][k]*v_j) * d3_k consumes h3_k in place.
//   - h1/h2 recomputed bit-identically in backward; g2->a fused.
// NOT bit-identical to reference order only in the g5 factoring (~1 ulp);
// scored in bf16 (quantum 0.03125, threshold 0.12125) - R8 passed at 0.03125.
// ---------------------------------------------------------------------------

// repetition macros: A-suffix for outer loops, B-suffix for inner loops
// (cpp will not re-expand a macro inside itself, so the copies are required)
#define R16A(M) M(0) M(1) M(2) M(3) M(4) M(5) M(6) M(7) M(8) M(9) M(10) M(11) M(12) M(13) M(14) M(15)
#define R32A(M) R16A(M) M(16) M(17) M(18) M(19) M(20) M(21) M(22) M(23) M(24) M(25) M(26) M(27) M(28) M(29) M(30) M(31)
#define R16B(M) M(0) M(1) M(2) M(3) M(4) M(5) M(6) M(7) M(8) M(9) M(10) M(11) M(12) M(13) M(14) M(15)
#define R32B(M) R16B(M) M(16) M(17) M(18) M(19) M(20) M(21) M(22) M(23) M(24) M(25) M(26) M(27) M(28) M(29) M(30) M(31)

#define ELU(z) ((z) > 0.0f ? (z) : (__expf(z) - 1.0f))
// elu derivative from elu output: d = (z>0) ? 1 : exp(z); for z<=0,
// h = exp(z)-1  =>  d = h+1 (bit-matches prior kernels' DFROMH)
#define DFROMH(h) ((h) > 0.0f ? 1.0f : (h) + 1.0f)

__device__ __forceinline__ uint32_t rotl32(uint32_t v, uint32_t r) {
  return (v << r) | (v >> (32u - r));
}

// JAX threefry2x32 (20 rounds), matches jax/_src/prng.py
__device__ __forceinline__ void tf2x32(uint32_t k0, uint32_t k1,
                                       uint32_t x0, uint32_t x1,
                                       uint32_t& o0, uint32_t& o1) {
  uint32_t k2 = k0 ^ k1 ^ 0x1BD11BDAu;
  x0 += k0; x1 += k1;
#define TF_R(r) { x0 += x1; x1 = rotl32(x1, r); x1 ^= x0; }
  TF_R(13) TF_R(15) TF_R(26) TF_R(6)   x0 += k1; x1 += k2 + 1u;
  TF_R(17) TF_R(29) TF_R(16) TF_R(24)  x0 += k2; x1 += k0 + 2u;
  TF_R(13) TF_R(15) TF_R(26) TF_R(6)   x0 += k0; x1 += k1 + 3u;
  TF_R(17) TF_R(29) TF_R(16) TF_R(24)  x0 += k1; x1 += k2 + 4u;
  TF_R(13) TF_R(15) TF_R(26) TF_R(6)   x0 += k2; x1 += k0 + 5u;
#undef TF_R
  o0 = x0; o1 = x1;
}

// XLA f32 ErfInv (Giles 2012 polynomial) — what lax.erf_inv lowers to
__device__ __forceinline__ float erfinv_f32(float x) {
  float w = -log1pf(-(x * x));
  float p;
  if (w < 5.0f) {
    w = w - 2.5f;
    p = 2.81022636e-08f;
    p = fmaf(p, w, 3.43273939e-07f);
    p = fmaf(p, w, -3.5233877e-06f);
    p = fmaf(p, w, -4.39150654e-06f);
    p = fmaf(p, w, 0.00021858087f);
    p = fmaf(p, w, -0.00125372503f);
    p = fmaf(p, w, -0.00417768164f);
    p = fmaf(p, w, 0.246640727f);
    p = fmaf(p, w, 1.50140941f);
  } else {
    w = sqrtf(w) - 3.0f;
    p = -0.000200214257f;
    p = fmaf(p, w, 0.000100950558f);
    p = fmaf(p, w, 0.00134934322f);
    p = fmaf(p, w, -0.00367342844f);
    p = fmaf(p, w, 0.00573950773f);
    p = fmaf(p, w, -0.0076224613f);
    p = fmaf(p, w, 0.00943887047f);
    p = fmaf(p, w, 1.00167406f);
    p = fmaf(p, w, 2.83297682f);
  }
  return p * x;
}

// jax.random.normal for one flat element index f under key (k0,k1)
__device__ __forceinline__ float jax_normal_elem(uint32_t k0, uint32_t k1,
                                                 uint32_t f) {
  uint32_t o0, o1, bits;
  if (f < HALF_CNT) {
    tf2x32(k0, k1, f, f + HALF_CNT, o0, o1);
    bits = o0;
  } else {
    tf2x32(k0, k1, f - HALF_CNT, f, o0, o1);
    bits = o1;
  }
  float u01 = __uint_as_float((bits >> 9) | 0x3f800000u) - 1.0f;
  const float lo = -0.99999994f;           // nextafter(-1, 0) in f32
  float v = fmaxf(lo, fmaf(u01, 2.0f, lo));
  return 1.41421356237309515f * erfinv_f32(v);
}

__global__ __launch_bounds__(256, 2)
void phinn_kernel(
    const float* __restrict__ x,
    const float* __restrict__ W1, const float* __restrict__ b1,
    const float* __restrict__ W2, const float* __restrict__ b2,
    const float* __restrict__ W3, const float* __restrict__ b3,
    const float* __restrict__ W4, const float* __restrict__ b4,
    const float* __restrict__ W5, const float* __restrict__ b5,
    const float* __restrict__ Wt,
    const float* __restrict__ dtp, const int* __restrict__ nstepsp,
    float* __restrict__ out) {
  const int tx = threadIdx.x;
  const int bx = blockIdx.x;
  const int tid = (bx << 8) + tx;            // 0 .. B*N-1
  const int bidx = bx >> 3;                  // uniform per block (N/256 = 8)
  const int nidx = ((bx & 7) << 8) + tx;

  const float dt = dtp[0];
  const int nsteps = nstepsp[0];
  const float sqdt = sqrtf(dt);

  const float* xr = x + (size_t)bidx * ROWLEN;   // uniform -> s_loads
  float tt = xr[0];
  float y0 = xr[2 + nidx * 2 + 0];
  float y1 = xr[2 + nidx * 2 + 1];
  const float tcrit = xr[2 + NN * DD + 0];

  // Hoisted tilt products: same fmafs as the in-loop original, with the
  // pre/post select moved AFTER the arithmetic (bit-identical values).
  const float sp0 = xr[2 + NN * DD + 1];
  const float sp1 = xr[2 + NN * DD + 2];
  const float sq0 = xr[2 + NN * DD + 3];
  const float sq1 = xr[2 + NN * DD + 4];
  const float wt00 = Wt[0], wt01 = Wt[1], wt10 = Wt[2], wt11 = Wt[3];
  const float tp0 = fmaf(sp0, wt00, sp1 * wt01);
  const float tp1 = fmaf(sp0, wt10, sp1 * wt11);
  const float tq0 = fmaf(sq0, wt00, sq1 * wt01);
  const float tq1 = fmaf(sq0, wt10, sq1 * wt11);

  const uint32_t f0 = (uint32_t)(tid << 1);  // flat idx of component 0

  // named scalar activation state (no arrays, no vectors, no LDS)
#define D_H1(j) float h1_##j;
#define D_H2(j) float h2_##j;
#define D_H3(j) float h3_##j;
#define D_V(j)  float v_##j;
#define D_G3(j) float g3_##j;
#define D_A(j)  float a_##j;
  R16A(D_H1)
  R32A(D_H2)
  R32A(D_H3)
  R16A(D_V)
  R32A(D_G3)
  R16A(D_A)

  for (int i = 0; i < nsteps; ++i) {
    // ---- forward: 2 -> 16 -> 32 -> 32 -> 16 -> 1 ----
    // h1 (dropped after h2; recomputed bit-identically in backward)
#define S_H1(j) { float z = fmaf(W1[2*j+0], y0, fmaf(W1[2*j+1], y1, b1[j])); h1_##j = ELU(z); }
    R16A(S_H1)

    // h2 (dropped after h3; recomputed per-element in backward)
#define MAC_H2(k) z = fmaf(W2[16*J+k], h1_##k, z);
#define S_H2(j) { const int J = j; float z = b2[J]; R16B(MAC_H2) h2_##j = ELU(z); }
    R32A(S_H2)

    // h3 (kept in regs; consumed elementwise by the g3 loop below)
#define MAC_H3(k) z = fmaf(W3[32*J+k], h2_##k, z);
#define S_H3(j) { const int J = j; float z = b3[J]; R32B(MAC_H3) h3_##j = ELU(z); }
    R32A(S_H3)

    // layer 4 + 5 fused: h4 is a per-j TEMP. z5 accumulates in the same
    // j-order as the original separate loop (bit-identical z5); v_j = W5_j*d4_j
    // replaces h4/g4 as live state (16 regs instead of 16+16).
    float z5 = b5[0];
#define MAC_H4(k) z = fmaf(W4[32*J+k], h3_##k, z);
#define S_H4V(j) { const int J = j; float z = b4[J]; R32B(MAC_H4) \
      float h4t = ELU(z); \
      z5 = fmaf(W5[J], h4t, z5); \
      v_##j = W5[J] * DFROMH(h4t); }
    R16A(S_H4V)

    // d softplus = sigmoid
    float g5 = 1.0f / (1.0f + __expf(-z5));

    // ---- backward (input-gradient) ----
    // g3_k = (g5 * sum_j W4[j][k]*v_j) * d3_k; h3_k dies as g3_k is born
    // (live h3-remaining + g3-produced stays exactly 32).
#define MAC_U(j) r = fmaf(W4[32*j+K], v_##j, r);
#define S_G3(k) { const int K = k; float r = 0.0f; R16B(MAC_U) \
      g3_##k = (g5 * r) * DFROMH(h3_##k); }
    R32A(S_G3)

    // recompute h1 from y (identical op sequence -> bit-identical values)
#define S_RH1(j) { float z = fmaf(W1[2*j+0], y0, fmaf(W1[2*j+1], y1, b1[j])); h1_##j = ELU(z); }
    R16A(S_RH1)

    // fused g2 -> a: for each j, produce g2_j (recomputing h2_j bit-exactly),
    // then immediately fold it into a_k = sum_j W2[16j+k]*g2_j.
#define Z_A(k) a_##k = 0.0f;
    R16A(Z_A)
#define MAC_T(i) tsum = fmaf(W3[32*i+J], g3_##i, tsum);
#define MAC_Z2(k) z2 = fmaf(W2[16*J+k], h1_##k, z2);
#define MAC_A(k) a_##k = fmaf(W2[16*J+k], g2j, a_##k);
#define S_G2(j) { const int J = j; \
      float tsum = 0.0f; R32B(MAC_T) \
      float z2 = b2[J]; R16B(MAC_Z2) \
      float h2r = ELU(z2); \
      float g2j = tsum * DFROMH(h2r); \
      R16B(MAC_A) }
    R32A(S_G2)

    // g1 and input-gradient, fused (same fmaf chain order as original)
    float gy0 = 0.0f, gy1 = 0.0f;
#define MAC_GY(j) { float g1j = a_##j * DFROMH(h1_##j); \
      gy0 = fmaf(W1[2*j+0], g1j, gy0); \
      gy1 = fmaf(W1[2*j+1], g1j, gy1); }
    R16A(MAC_GY)

    // ---- tilt (hoisted products, select only) ----
    bool pre = tt < tcrit;
    float tilt0 = pre ? tp0 : tq0;
    float tilt1 = pre ? tp1 : tq1;

    // ---- per-step key, computed only now so k0/k1 aren't live in the MLP
    // fold_in(key(42), i) = threefry((0,42), (0,i)); uniform across threads
    uint32_t k0, k1;
    tf2x32(0u, 42u, 0u, (uint32_t)i, k0, k1);

    // ---- noise (exact JAX threefry normal) ----
    float nz0 = jax_normal_elem(k0, k1, f0);
    float nz1 = jax_normal_elem(k0, k1, f0 + 1u);

    // ---- Euler-Maruyama update ----
    float drift0 = -(gy0 + tilt0);
    float drift1 = -(gy1 + tilt1);
    y0 = y0 + drift0 * dt + SIGMA_C * (nz0 * sqdt);
    y1 = y1 + drift1 * dt + SIGMA_C * (nz1 * sqdt);
    tt += dt;
  }

  out[(size_t)tid * 2 + 0] = y0;
  out[(size_t)tid * 2 + 1] = y1;
}

extern "C" void kernel_launch(void* const* d_in, const int* in_sizes, int n_in,
                              void* d_out, int out_size, void* d_ws,
                              size_t ws_size, hipStream_t stream) {
  const float* x  = (const float*)d_in[0];
  const float* W1 = (const float*)d_in[1];
  const float* b1 = (const float*)d_in[2];
  const float* W2 = (const float*)d_in[3];
  const float* b2 = (const float*)d_in[4];
  const float* W3 = (const float*)d_in[5];
  const float* b3 = (const float*)d_in[6];
  const float* W4 = (const float*)d_in[7];
  const float* b4 = (const float*)d_in[8];
  const float* W5 = (const float*)d_in[9];
  const float* b5 = (const float*)d_in[10];
  const float* Wt = (const float*)d_in[11];
  const float* dt = (const float*)d_in[12];
  const int* nsteps = (const int*)d_in[13];
  float* out = (float*)d_out;

  dim3 grid((BB * NN) / 256);
  dim3 block(256);
  hipLaunchKernelGGL(phinn_kernel, grid, block, 0, stream,
                     x, W1, b1, W2, b2, W3, b3, W4, b4, W5, b5, Wt, dt, nsteps,
                     out);
}